// Round 4
// baseline (505.850 us; speedup 1.0000x reference)
//
#include <hip/hip_runtime.h>
#include <hip/hip_bf16.h>
#include <stdint.h>
#include <stddef.h>

// Problem: B=4096, E=16, D=512, H=2048
// out[b,h] = sum_e relu( x_b . W[e,h,:] - c_e . W[e,h,:] + b[e,h] )
// GEMM view: M=4096, N=E*H (expert-looped), K=512. 137.4 GFLOP.
// MFMA floor ~58-66 us/CU-sweep. R2/R3: 172 us (790 TF) at 2 waves/SIMD.
// R4: B bypasses LDS (single-use data), A-only LDS, 4 blocks/CU.

#define B_DIM 4096
#define E_DIM 16
#define D_DIM 512
#define H_DIM 2048

typedef short bf16x8 __attribute__((ext_vector_type(8)));
typedef float f32x4 __attribute__((ext_vector_type(4)));

__device__ __forceinline__ short f2bf(float f) {
  __hip_bfloat16 h = __float2bfloat16(f);  // RNE
  return *reinterpret_cast<short*>(&h);
}

__device__ __forceinline__ bf16x8 cvt8(float4 a, float4 b) {
  bf16x8 v;
  v[0] = f2bf(a.x); v[1] = f2bf(a.y); v[2] = f2bf(a.z); v[3] = f2bf(a.w);
  v[4] = f2bf(b.x); v[5] = f2bf(b.y); v[6] = f2bf(b.z); v[7] = f2bf(b.w);
  return v;
}

// async global->LDS, 16 bytes per lane. LDS dest must be uniform_base + lane*16.
__device__ __forceinline__ void async_copy16(const void* gptr, void* lptr) {
  __builtin_amdgcn_global_load_lds(
      (const __attribute__((address_space(1))) void*)gptr,
      (__attribute__((address_space(3))) void*)lptr,
      16, 0, 0);
}

// ---------------------------------------------------------------------------
// Merged prepass. Blocks [0,8192): one wave per W row (e,h): convert row to
// bf16 + bias2[e,h] = b[e,h] - dot(c_e, W row). Blocks [8192,9216): convert x.
// ---------------------------------------------------------------------------
__global__ __launch_bounds__(256) void prep(
    const float* __restrict__ W, const float* __restrict__ C,
    const float* __restrict__ bias, const float* __restrict__ X,
    __hip_bfloat16* __restrict__ Wb, float* __restrict__ bias2,
    __hip_bfloat16* __restrict__ Xb) {
  if (blockIdx.x < 8192) {
    const int gw = (blockIdx.x * 256 + threadIdx.x) >> 6;  // W row id
    const int lane = threadIdx.x & 63;
    const int e = gw >> 11;  // / H_DIM

    const float* wr = W + (size_t)gw * D_DIM + lane * 8;
    const float* cr = C + (size_t)e * D_DIM + lane * 8;
    float4 w0 = *(const float4*)(wr);
    float4 w1 = *(const float4*)(wr + 4);
    float4 c0 = *(const float4*)(cr);
    float4 c1 = *(const float4*)(cr + 4);

    *(bf16x8*)(Wb + (size_t)gw * D_DIM + lane * 8) = cvt8(w0, w1);

    float dot = w0.x * c0.x + w0.y * c0.y + w0.z * c0.z + w0.w * c0.w +
                w1.x * c1.x + w1.y * c1.y + w1.z * c1.z + w1.w * c1.w;
#pragma unroll
    for (int off = 32; off > 0; off >>= 1) dot += __shfl_down(dot, off, 64);
    if (lane == 0) bias2[gw] = bias[gw] - dot;
  } else {
    const size_t i = ((size_t)(blockIdx.x - 8192) * 256 + threadIdx.x) * 8;
    float4 a = *(const float4*)(X + i);
    float4 b = *(const float4*)(X + i + 4);
    *(bf16x8*)(Xb + i) = cvt8(a, b);
  }
}

// ---------------------------------------------------------------------------
// Main kernel R4: tile m=128 x n=64, 4 waves (2x2), wave = 64m x 32n per
// expert, 2 experts per K-pass. B-fragments loaded DIRECTLY from global
// (16B/lane, L2-resident W slice) -- no LDS round-trip for single-use data.
// A (X, reused 16x per block) staged via LDS, double-buffered, BK=32.
// acc footprint 96 f32 -> 4 blocks/CU (16 waves, 4/SIMD): barriers of 4
// independent blocks interleave on each SIMD.
// Grid = 1024 (mi 32 x hi 32); blk%8 == hi%8 -> W-slice stays on one XCD L2.
// ---------------------------------------------------------------------------
__global__ __launch_bounds__(256, 4) void moe_gemm(
    const __hip_bfloat16* __restrict__ Xb,   // [4096, 512]
    const __hip_bfloat16* __restrict__ Wb,   // [16, 2048, 512]
    const float* __restrict__ bias2,         // [16, 2048]
    float* __restrict__ out) {               // [4096, 2048]
  __shared__ __align__(16) __hip_bfloat16 As[2][128 * 32];  // 16 KB
  __shared__ __align__(16) float biasS[E_DIM * 64];         // 4 KB

  const int tid = threadIdx.x;
  const int lane = tid & 63;
  const int wave = tid >> 6;
  const int hi = blockIdx.x & 31;
  const int mi = blockIdx.x >> 5;
  const int m0 = mi * 128;
  const int h0 = hi * 64;

  // preload bias2 for this h-tile (64 cols), all 16 experts
  for (int idx = tid; idx < E_DIM * 64; idx += 256) {
    biasS[idx] = bias2[((idx >> 6) << 11) + h0 + (idx & 63)];
  }

  const int wm = (wave & 1) * 64;
  const int wn = (wave >> 1) * 32;
  const int lm = lane & 15;
  const int q = lane >> 4;

  // ---- A staging: thread t handles 16B chunks t and t+256 of the 8KB tile
  const int r = tid >> 2;             // rows 0..63 (and +64)
  const int col = (tid & 3) << 3;     // k elem offset 0/8/16/24
  const size_t aOff0 = (size_t)(m0 + r) * D_DIM + col;
  const size_t aOff1 = (size_t)(m0 + r + 64) * D_DIM + col;
  const int ld0 = tid * 8;
  const int ld1 = (tid + 256) * 8;

  // ---- A-fragment LDS read offsets (row-major [128][32])
  int offA[4];
#pragma unroll
  for (int i = 0; i < 4; ++i) offA[i] = (wm + i * 16 + lm) * 32 + q * 8;

  // ---- B direct-load base: row (h0+wn+j*16+lm), k-chunk q*8. 16B aligned.
  const size_t bBase = (size_t)(h0 + wn + lm) * D_DIM + q * 8;

  f32x4 sum[4][2], acc0[4][2], acc1[4][2];
#pragma unroll
  for (int i = 0; i < 4; ++i)
#pragma unroll
    for (int j = 0; j < 2; ++j) {
      sum[i][j] = (f32x4){0.f, 0.f, 0.f, 0.f};
      acc0[i][j] = (f32x4){0.f, 0.f, 0.f, 0.f};
      acc1[i][j] = (f32x4){0.f, 0.f, 0.f, 0.f};
    }

  // stage A k-chunk kidx (0..15) into buffer buf
#define STAGE_A(buf, kidx)                                        \
  {                                                               \
    const int kk = (kidx) << 5;                                   \
    async_copy16(Xb + aOff0 + kk, &As[buf][ld0]);                 \
    async_copy16(Xb + aOff1 + kk, &As[buf][ld1]);                 \
  }

  STAGE_A(0, 0);
  __syncthreads();  // buffer 0 ready

  for (int pair = 0; pair < 8; ++pair) {
    const __hip_bfloat16* B0 = Wb + ((size_t)(2 * pair) << 20) + bBase;
    const __hip_bfloat16* B1 = B0 + ((size_t)1 << 20);

#pragma unroll
    for (int ks = 0; ks < 16; ++ks) {
      const int t = pair * 16 + ks;
      const int cur = t & 1;
      if (t < 127) STAGE_A(cur ^ 1, (t + 1) & 15);

      const int kk = ks << 5;
      // B fragments: direct from global (L2-hot W slice)
      bf16x8 b00 = *(const bf16x8*)(B0 + kk);
      bf16x8 b01 = *(const bf16x8*)(B0 + kk + 16 * D_DIM);
      bf16x8 b10 = *(const bf16x8*)(B1 + kk);
      bf16x8 b11 = *(const bf16x8*)(B1 + kk + 16 * D_DIM);

      bf16x8 af[4];
#pragma unroll
      for (int i = 0; i < 4; ++i) af[i] = *(const bf16x8*)&As[cur][offA[i]];

#pragma unroll
      for (int i = 0; i < 4; ++i) {
        acc0[i][0] = __builtin_amdgcn_mfma_f32_16x16x32_bf16(af[i], b00, acc0[i][0], 0, 0, 0);
        acc0[i][1] = __builtin_amdgcn_mfma_f32_16x16x32_bf16(af[i], b01, acc0[i][1], 0, 0, 0);
        acc1[i][0] = __builtin_amdgcn_mfma_f32_16x16x32_bf16(af[i], b10, acc1[i][0], 0, 0, 0);
        acc1[i][1] = __builtin_amdgcn_mfma_f32_16x16x32_bf16(af[i], b11, acc1[i][1], 0, 0, 0);
      }

      __syncthreads();  // readers done before next overwrite; drains prefetch
    }

    // expert-pair epilogue: relu + accumulate, reset accs
#pragma unroll
    for (int j = 0; j < 2; ++j) {
      const float bv0 = biasS[(2 * pair) * 64 + wn + j * 16 + lm];
      const float bv1 = biasS[(2 * pair + 1) * 64 + wn + j * 16 + lm];
#pragma unroll
      for (int i = 0; i < 4; ++i)
#pragma unroll
        for (int u = 0; u < 4; ++u) {
          sum[i][j][u] += fmaxf(acc0[i][j][u] + bv0, 0.f) +
                          fmaxf(acc1[i][j][u] + bv1, 0.f);
          acc0[i][j][u] = 0.f;
          acc1[i][j][u] = 0.f;
        }
    }
  }
#undef STAGE_A

  // write: C/D layout col=lane&15, row=(lane>>4)*4+reg  [verified m89/m91]
  const int rbase = q * 4;
#pragma unroll
  for (int i = 0; i < 4; ++i)
#pragma unroll
    for (int j = 0; j < 2; ++j)
#pragma unroll
      for (int u = 0; u < 4; ++u)
        out[(size_t)(m0 + wm + i * 16 + rbase + u) * H_DIM + h0 + wn + j * 16 + lm] =
            sum[i][j][u];
}

// ---------------------------------------------------------------------------
// Fallback (only if workspace too small): naive but correct fp32.
// ---------------------------------------------------------------------------
__global__ __launch_bounds__(256) void naive_kernel(
    const float* __restrict__ x, const float* __restrict__ c,
    const float* __restrict__ W, const float* __restrict__ bias,
    float* __restrict__ out) {
  const int idx = blockIdx.x * 256 + threadIdx.x;
  const int b = idx >> 11;
  const int h = idx & (H_DIM - 1);
  const float* xr = x + (size_t)b * D_DIM;
  float s = 0.f;
  for (int e = 0; e < E_DIM; ++e) {
    const float* wr = W + ((size_t)e * H_DIM + h) * D_DIM;
    const float* cr = c + (size_t)e * D_DIM;
    float acc = bias[e * H_DIM + h];
    for (int d = 0; d < D_DIM; ++d) acc += (xr[d] - cr[d]) * wr[d];
    s += fmaxf(acc, 0.f);
  }
  out[idx] = s;
}

extern "C" void kernel_launch(void* const* d_in, const int* in_sizes, int n_in,
                              void* d_out, int out_size, void* d_ws, size_t ws_size,
                              hipStream_t stream) {
  const float* x = (const float*)d_in[0];     // [4096, 512]
  const float* c = (const float*)d_in[1];     // [16, 512]
  const float* W = (const float*)d_in[2];     // [16, 2048, 512]
  const float* b = (const float*)d_in[3];     // [16, 2048]
  float* out = (float*)d_out;                 // [4096, 2048]

  const size_t sz_wb = (size_t)E_DIM * H_DIM * D_DIM * 2;  // 32 MB
  const size_t sz_xb = (size_t)B_DIM * D_DIM * 2;          // 4 MB
  const size_t sz_b2 = (size_t)E_DIM * H_DIM * 4;          // 128 KB
  const size_t need = sz_wb + sz_xb + sz_b2;

  if (ws_size >= need) {
    __hip_bfloat16* Wb = (__hip_bfloat16*)((char*)d_ws);
    __hip_bfloat16* Xb = (__hip_bfloat16*)((char*)d_ws + sz_wb);
    float* bias2 = (float*)((char*)d_ws + sz_wb + sz_xb);
    prep<<<9216, 256, 0, stream>>>(W, c, b, x, Wb, bias2, Xb);
    moe_gemm<<<1024, 256, 0, stream>>>(Xb, Wb, bias2, out);
  } else {
    naive_kernel<<<(B_DIM * H_DIM) / 256, 256, 0, stream>>>(x, c, W, b, out);
  }
}

// Round 5
// 263.178 us; speedup vs baseline: 1.9221x; 1.9221x over previous
//
#include <hip/hip_runtime.h>
#include <hip/hip_bf16.h>
#include <stdint.h>
#include <stddef.h>

// Problem: B=4096, E=16, D=512, H=2048
// out[b,h] = sum_e relu( x_b . W[e,h,:] - c_e . W[e,h,:] + b[e,h] )
// GEMM view: M=4096, N=E*H (expert-looped), K=512. 137.4 GFLOP.
// R2/R3: 128x128 tile, grid 512 = 2 blocks/CU -> 172 us, latency-bound
// (MFMA 35%, LDS ~44%, nothing saturated). R4 (B direct-global) cratered:
// L2 thrash, 533MB HBM. R5: B back in LDS; tile 128x64, grid 1024 =
// 4 blocks/CU for real latency hiding.

#define B_DIM 4096
#define E_DIM 16
#define D_DIM 512
#define H_DIM 2048

typedef short bf16x8 __attribute__((ext_vector_type(8)));
typedef float f32x4 __attribute__((ext_vector_type(4)));

__device__ __forceinline__ short f2bf(float f) {
  __hip_bfloat16 h = __float2bfloat16(f);  // RNE
  return *reinterpret_cast<short*>(&h);
}

__device__ __forceinline__ bf16x8 cvt8(float4 a, float4 b) {
  bf16x8 v;
  v[0] = f2bf(a.x); v[1] = f2bf(a.y); v[2] = f2bf(a.z); v[3] = f2bf(a.w);
  v[4] = f2bf(b.x); v[5] = f2bf(b.y); v[6] = f2bf(b.z); v[7] = f2bf(b.w);
  return v;
}

// async global->LDS, 16 bytes per lane. LDS dest must be uniform_base + lane*16.
__device__ __forceinline__ void async_copy16(const void* gptr, void* lptr) {
  __builtin_amdgcn_global_load_lds(
      (const __attribute__((address_space(1))) void*)gptr,
      (__attribute__((address_space(3))) void*)lptr,
      16, 0, 0);
}

// ---------------------------------------------------------------------------
// Merged prepass. Blocks [0,8192): one wave per W row (e,h): convert row to
// bf16 + bias2[e,h] = b[e,h] - dot(c_e, W row). Blocks [8192,9216): convert x.
// ---------------------------------------------------------------------------
__global__ __launch_bounds__(256) void prep(
    const float* __restrict__ W, const float* __restrict__ C,
    const float* __restrict__ bias, const float* __restrict__ X,
    __hip_bfloat16* __restrict__ Wb, float* __restrict__ bias2,
    __hip_bfloat16* __restrict__ Xb) {
  if (blockIdx.x < 8192) {
    const int gw = (blockIdx.x * 256 + threadIdx.x) >> 6;  // W row id
    const int lane = threadIdx.x & 63;
    const int e = gw >> 11;  // / H_DIM

    const float* wr = W + (size_t)gw * D_DIM + lane * 8;
    const float* cr = C + (size_t)e * D_DIM + lane * 8;
    float4 w0 = *(const float4*)(wr);
    float4 w1 = *(const float4*)(wr + 4);
    float4 c0 = *(const float4*)(cr);
    float4 c1 = *(const float4*)(cr + 4);

    *(bf16x8*)(Wb + (size_t)gw * D_DIM + lane * 8) = cvt8(w0, w1);

    float dot = w0.x * c0.x + w0.y * c0.y + w0.z * c0.z + w0.w * c0.w +
                w1.x * c1.x + w1.y * c1.y + w1.z * c1.z + w1.w * c1.w;
#pragma unroll
    for (int off = 32; off > 0; off >>= 1) dot += __shfl_down(dot, off, 64);
    if (lane == 0) bias2[gw] = bias[gw] - dot;
  } else {
    const size_t i = ((size_t)(blockIdx.x - 8192) * 256 + threadIdx.x) * 8;
    float4 a = *(const float4*)(X + i);
    float4 b = *(const float4*)(X + i + 4);
    *(bf16x8*)(Xb + i) = cvt8(a, b);
  }
}

// ---------------------------------------------------------------------------
// Main kernel R5: tile m=128 x n=64, 4 waves (2m x 2n), wave = 64m x 32n per
// expert, 2 experts per K-pass (shared A fragments). A and both B tiles in
// LDS, double-buffered, one barrier per phase. 128 phases (8 pairs x 16 ks).
// LDS 36 KB, accumulators 96 f32/thread (acc0/acc1 -> AGPRs) => 4 blocks/CU.
// Grid = 1024 (mi 32 x hi 32); blk%8 == hi%8 -> W h-slice pinned to one XCD.
// ---------------------------------------------------------------------------
__global__ __launch_bounds__(256, 4) void moe_gemm(
    const __hip_bfloat16* __restrict__ Xb,   // [4096, 512]
    const __hip_bfloat16* __restrict__ Wb,   // [16, 2048, 512]
    const float* __restrict__ bias2,         // [16, 2048]
    float* __restrict__ out) {               // [4096, 2048]
  __shared__ __align__(16) __hip_bfloat16 As[2][128 * 32];     // 16 KB
  __shared__ __align__(16) __hip_bfloat16 Bs[2][2][64 * 32];   // 16 KB
  __shared__ __align__(16) float biasS[E_DIM * 64];            // 4 KB

  const int tid = threadIdx.x;
  const int lane = tid & 63;
  const int wave = tid >> 6;
  const int hi = blockIdx.x & 31;
  const int mi = blockIdx.x >> 5;
  const int m0 = mi * 128;
  const int h0 = hi * 64;

  // preload bias2 for this h-tile (64 cols), all 16 experts
  for (int idx = tid; idx < E_DIM * 64; idx += 256) {
    biasS[idx] = bias2[((idx >> 6) << 11) + h0 + (idx & 63)];
  }

  const int wm = (wave & 1) * 64;
  const int wn = (wave >> 1) * 32;
  const int lm = lane & 15;
  const int q = lane >> 4;

  // ---- staging: thread t handles A chunks t,t+256 and B0/B1 chunk t.
  const int r = tid >> 2;             // rows 0..63
  const int col = (tid & 3) << 3;     // k elem offset 0/8/16/24
  const size_t aOff0 = (size_t)(m0 + r) * D_DIM + col;
  const size_t aOff1 = (size_t)(m0 + r + 64) * D_DIM + col;
  const size_t bOff = (size_t)(h0 + r) * D_DIM + col;  // B rows 0..63
  const int ldA0 = tid * 8;
  const int ldA1 = (tid + 256) * 8;
  const int ldB = tid * 8;

  // ---- read-side element offsets (row-major [rows][32])
  int offA[4], offB[2];
#pragma unroll
  for (int i = 0; i < 4; ++i) offA[i] = (wm + i * 16 + lm) * 32 + q * 8;
#pragma unroll
  for (int j = 0; j < 2; ++j) offB[j] = (wn + j * 16 + lm) * 32 + q * 8;

  f32x4 sum[4][2], acc0[4][2], acc1[4][2];
#pragma unroll
  for (int i = 0; i < 4; ++i)
#pragma unroll
    for (int j = 0; j < 2; ++j) {
      sum[i][j] = (f32x4){0.f, 0.f, 0.f, 0.f};
      acc0[i][j] = (f32x4){0.f, 0.f, 0.f, 0.f};
      acc1[i][j] = (f32x4){0.f, 0.f, 0.f, 0.f};
    }

  // phase t: pair = t>>4, ks = t&15. stage(t) fills buffer t&1.
#define STAGE(buf, tt)                                                      \
  {                                                                         \
    const int kk = ((tt) & 15) << 5;                                        \
    const __hip_bfloat16* Bb = Wb + ((size_t)((tt) >> 4) << 21) + bOff + kk;\
    async_copy16(Xb + aOff0 + kk, &As[buf][ldA0]);                          \
    async_copy16(Xb + aOff1 + kk, &As[buf][ldA1]);                          \
    async_copy16(Bb, &Bs[buf][0][ldB]);                                     \
    async_copy16(Bb + ((size_t)1 << 20), &Bs[buf][1][ldB]);                 \
  }

  STAGE(0, 0);
  __syncthreads();  // buffer 0 ready

  for (int t = 0; t < 128; ++t) {
    const int cur = t & 1;
    if (t < 127) STAGE(cur ^ 1, t + 1);  // prefetch next phase

    bf16x8 af[4];
#pragma unroll
    for (int i = 0; i < 4; ++i) af[i] = *(const bf16x8*)&As[cur][offA[i]];

#pragma unroll
    for (int j = 0; j < 2; ++j) {
      const bf16x8 b0 = *(const bf16x8*)&Bs[cur][0][offB[j]];
#pragma unroll
      for (int i = 0; i < 4; ++i)
        acc0[i][j] = __builtin_amdgcn_mfma_f32_16x16x32_bf16(
            af[i], b0, acc0[i][j], 0, 0, 0);
      const bf16x8 b1 = *(const bf16x8*)&Bs[cur][1][offB[j]];
#pragma unroll
      for (int i = 0; i < 4; ++i)
        acc1[i][j] = __builtin_amdgcn_mfma_f32_16x16x32_bf16(
            af[i], b1, acc1[i][j], 0, 0, 0);
    }

    if ((t & 15) == 15) {  // expert-pair epilogue (uniform branch)
      const int pair = t >> 4;
#pragma unroll
      for (int j = 0; j < 2; ++j) {
        const float bv0 = biasS[(2 * pair) * 64 + wn + j * 16 + lm];
        const float bv1 = biasS[(2 * pair + 1) * 64 + wn + j * 16 + lm];
#pragma unroll
        for (int i = 0; i < 4; ++i)
#pragma unroll
          for (int u = 0; u < 4; ++u) {
            sum[i][j][u] += fmaxf(acc0[i][j][u] + bv0, 0.f) +
                            fmaxf(acc1[i][j][u] + bv1, 0.f);
            acc0[i][j][u] = 0.f;
            acc1[i][j][u] = 0.f;
          }
      }
    }

    __syncthreads();  // drains prefetch (overlapped); guards buf reuse
  }
#undef STAGE

  // write: C/D layout col=lane&15, row=(lane>>4)*4+reg  [verified m89/m91]
  const int rbase = q * 4;
#pragma unroll
  for (int i = 0; i < 4; ++i)
#pragma unroll
    for (int j = 0; j < 2; ++j)
#pragma unroll
      for (int u = 0; u < 4; ++u)
        out[(size_t)(m0 + wm + i * 16 + rbase + u) * H_DIM + h0 + wn + j * 16 + lm] =
            sum[i][j][u];
}

// ---------------------------------------------------------------------------
// Fallback (only if workspace too small): naive but correct fp32.
// ---------------------------------------------------------------------------
__global__ __launch_bounds__(256) void naive_kernel(
    const float* __restrict__ x, const float* __restrict__ c,
    const float* __restrict__ W, const float* __restrict__ bias,
    float* __restrict__ out) {
  const int idx = blockIdx.x * 256 + threadIdx.x;
  const int b = idx >> 11;
  const int h = idx & (H_DIM - 1);
  const float* xr = x + (size_t)b * D_DIM;
  float s = 0.f;
  for (int e = 0; e < E_DIM; ++e) {
    const float* wr = W + ((size_t)e * H_DIM + h) * D_DIM;
    const float* cr = c + (size_t)e * D_DIM;
    float acc = bias[e * H_DIM + h];
    for (int d = 0; d < D_DIM; ++d) acc += (xr[d] - cr[d]) * wr[d];
    s += fmaxf(acc, 0.f);
  }
  out[idx] = s;
}

extern "C" void kernel_launch(void* const* d_in, const int* in_sizes, int n_in,
                              void* d_out, int out_size, void* d_ws, size_t ws_size,
                              hipStream_t stream) {
  const float* x = (const float*)d_in[0];     // [4096, 512]
  const float* c = (const float*)d_in[1];     // [16, 512]
  const float* W = (const float*)d_in[2];     // [16, 2048, 512]
  const float* b = (const float*)d_in[3];     // [16, 2048]
  float* out = (float*)d_out;                 // [4096, 2048]

  const size_t sz_wb = (size_t)E_DIM * H_DIM * D_DIM * 2;  // 32 MB
  const size_t sz_xb = (size_t)B_DIM * D_DIM * 2;          // 4 MB
  const size_t sz_b2 = (size_t)E_DIM * H_DIM * 4;          // 128 KB
  const size_t need = sz_wb + sz_xb + sz_b2;

  if (ws_size >= need) {
    __hip_bfloat16* Wb = (__hip_bfloat16*)((char*)d_ws);
    __hip_bfloat16* Xb = (__hip_bfloat16*)((char*)d_ws + sz_wb);
    float* bias2 = (float*)((char*)d_ws + sz_wb + sz_xb);
    prep<<<9216, 256, 0, stream>>>(W, c, b, x, Wb, bias2, Xb);
    moe_gemm<<<1024, 256, 0, stream>>>(Xb, Wb, bias2, out);
  } else {
    naive_kernel<<<(B_DIM * H_DIM) / 256, 256, 0, stream>>>(x, c, W, b, out);
  }
}

// Round 6
// 261.232 us; speedup vs baseline: 1.9364x; 1.0075x over previous
//
#include <hip/hip_runtime.h>
#include <hip/hip_bf16.h>
#include <stdint.h>
#include <stddef.h>

// Problem: B=4096, E=16, D=512, H=2048
// out[b,h] = sum_e relu( x_b . W[e,h,:] - c_e . W[e,h,:] + b[e,h] )
// GEMM view: M=4096, N=E*H (expert-looped), K=512. 137.4 GFLOP.
// R5: 168 us, LDS pipe ~81% busy (reads 197K + conflicts 65K + writes 65K
// cyc/CU of 402K). Conflict cause: [row][32] rows = 64B = 16 banks, so the
// 16-lane fragment read aliases lanes 2 apart to the same banks.
// R6: XOR swizzle chunk slot (row,q) holds k-chunk q ^ ((row>>1)&3) ->
// (row&1,(row>>1)&3) spans all 8 bank-start groups x2 = conflict-free b128.

#define B_DIM 4096
#define E_DIM 16
#define D_DIM 512
#define H_DIM 2048

typedef short bf16x8 __attribute__((ext_vector_type(8)));
typedef float f32x4 __attribute__((ext_vector_type(4)));

__device__ __forceinline__ short f2bf(float f) {
  __hip_bfloat16 h = __float2bfloat16(f);  // RNE
  return *reinterpret_cast<short*>(&h);
}

__device__ __forceinline__ bf16x8 cvt8(float4 a, float4 b) {
  bf16x8 v;
  v[0] = f2bf(a.x); v[1] = f2bf(a.y); v[2] = f2bf(a.z); v[3] = f2bf(a.w);
  v[4] = f2bf(b.x); v[5] = f2bf(b.y); v[6] = f2bf(b.z); v[7] = f2bf(b.w);
  return v;
}

// async global->LDS, 16 bytes per lane. LDS dest must be uniform_base + lane*16.
__device__ __forceinline__ void async_copy16(const void* gptr, void* lptr) {
  __builtin_amdgcn_global_load_lds(
      (const __attribute__((address_space(1))) void*)gptr,
      (__attribute__((address_space(3))) void*)lptr,
      16, 0, 0);
}

// ---------------------------------------------------------------------------
// Merged prepass. Blocks [0,8192): one wave per W row (e,h): convert row to
// bf16 + bias2[e,h] = b[e,h] - dot(c_e, W row). Blocks [8192,9216): convert x.
// ---------------------------------------------------------------------------
__global__ __launch_bounds__(256) void prep(
    const float* __restrict__ W, const float* __restrict__ C,
    const float* __restrict__ bias, const float* __restrict__ X,
    __hip_bfloat16* __restrict__ Wb, float* __restrict__ bias2,
    __hip_bfloat16* __restrict__ Xb) {
  if (blockIdx.x < 8192) {
    const int gw = (blockIdx.x * 256 + threadIdx.x) >> 6;  // W row id
    const int lane = threadIdx.x & 63;
    const int e = gw >> 11;  // / H_DIM

    const float* wr = W + (size_t)gw * D_DIM + lane * 8;
    const float* cr = C + (size_t)e * D_DIM + lane * 8;
    float4 w0 = *(const float4*)(wr);
    float4 w1 = *(const float4*)(wr + 4);
    float4 c0 = *(const float4*)(cr);
    float4 c1 = *(const float4*)(cr + 4);

    *(bf16x8*)(Wb + (size_t)gw * D_DIM + lane * 8) = cvt8(w0, w1);

    float dot = w0.x * c0.x + w0.y * c0.y + w0.z * c0.z + w0.w * c0.w +
                w1.x * c1.x + w1.y * c1.y + w1.z * c1.z + w1.w * c1.w;
#pragma unroll
    for (int off = 32; off > 0; off >>= 1) dot += __shfl_down(dot, off, 64);
    if (lane == 0) bias2[gw] = bias[gw] - dot;
  } else {
    const size_t i = ((size_t)(blockIdx.x - 8192) * 256 + threadIdx.x) * 8;
    float4 a = *(const float4*)(X + i);
    float4 b = *(const float4*)(X + i + 4);
    *(bf16x8*)(Xb + i) = cvt8(a, b);
  }
}

// ---------------------------------------------------------------------------
// Main kernel R6: tile m=128 x n=64, 4 waves (2m x 2n), wave = 64m x 32n per
// expert, 2 experts per K-pass (shared A fragments). A and both B tiles in
// LDS (double-buffered, one barrier per phase), XOR bank swizzle:
//   chunk slot (row, q) stores global k-chunk q ^ ((row>>1)&3).
// Staging side: thread t writes LDS chunk t = (row=t>>2, slot q=t&3), so it
// fetches global k-chunk (t&3) ^ ((row>>1)&3). Rows r and r+64 share f.
// Read side: fragment (row R, k-chunk q) found at slot q ^ ((R>>1)&3).
// LDS 36 KB, ~96 acc f32/thread => 4 blocks/CU. Grid 1024 (mi 32 x hi 32).
// ---------------------------------------------------------------------------
__global__ __launch_bounds__(256, 4) void moe_gemm(
    const __hip_bfloat16* __restrict__ Xb,   // [4096, 512]
    const __hip_bfloat16* __restrict__ Wb,   // [16, 2048, 512]
    const float* __restrict__ bias2,         // [16, 2048]
    float* __restrict__ out) {               // [4096, 2048]
  __shared__ __align__(16) __hip_bfloat16 As[2][128 * 32];     // 16 KB
  __shared__ __align__(16) __hip_bfloat16 Bs[2][2][64 * 32];   // 16 KB
  __shared__ __align__(16) float biasS[E_DIM * 64];            // 4 KB

  const int tid = threadIdx.x;
  const int lane = tid & 63;
  const int wave = tid >> 6;
  const int hi = blockIdx.x & 31;
  const int mi = blockIdx.x >> 5;
  const int m0 = mi * 128;
  const int h0 = hi * 64;

  // preload bias2 for this h-tile (64 cols), all 16 experts
  for (int idx = tid; idx < E_DIM * 64; idx += 256) {
    biasS[idx] = bias2[((idx >> 6) << 11) + h0 + (idx & 63)];
  }

  const int wm = (wave & 1) * 64;
  const int wn = (wave >> 1) * 32;
  const int lm = lane & 15;
  const int q = lane >> 4;

  // ---- staging: thread t handles A chunks t,t+256 and B0/B1 chunk t.
  // Swizzled source: fetch global k-chunk (t&3) ^ ((row>>1)&3).
  const int r = tid >> 2;                       // rows 0..63
  const int fr = (r >> 1) & 3;                  // same for row r and r+64
  const int col = (((tid & 3) ^ fr)) << 3;      // swizzled k elem offset
  const size_t aOff0 = (size_t)(m0 + r) * D_DIM + col;
  const size_t aOff1 = (size_t)(m0 + r + 64) * D_DIM + col;
  const size_t bOff = (size_t)(h0 + r) * D_DIM + col;  // B rows 0..63
  const int ldA0 = tid * 8;
  const int ldA1 = (tid + 256) * 8;
  const int ldB = tid * 8;

  // ---- read-side element offsets: (row R, k-chunk q) at slot q^((R>>1)&3)
  int offA[4], offB[2];
#pragma unroll
  for (int i = 0; i < 4; ++i) {
    const int R = wm + i * 16 + lm;
    offA[i] = R * 32 + ((q ^ ((R >> 1) & 3)) << 3);
  }
#pragma unroll
  for (int j = 0; j < 2; ++j) {
    const int R = wn + j * 16 + lm;
    offB[j] = R * 32 + ((q ^ ((R >> 1) & 3)) << 3);
  }

  f32x4 sum[4][2], acc0[4][2], acc1[4][2];
#pragma unroll
  for (int i = 0; i < 4; ++i)
#pragma unroll
    for (int j = 0; j < 2; ++j) {
      sum[i][j] = (f32x4){0.f, 0.f, 0.f, 0.f};
      acc0[i][j] = (f32x4){0.f, 0.f, 0.f, 0.f};
      acc1[i][j] = (f32x4){0.f, 0.f, 0.f, 0.f};
    }

  // phase t: pair = t>>4, ks = t&15. stage(t) fills buffer t&1.
#define STAGE(buf, tt)                                                      \
  {                                                                         \
    const int kk = ((tt) & 15) << 5;                                        \
    const __hip_bfloat16* Bb = Wb + ((size_t)((tt) >> 4) << 21) + bOff + kk;\
    async_copy16(Xb + aOff0 + kk, &As[buf][ldA0]);                          \
    async_copy16(Xb + aOff1 + kk, &As[buf][ldA1]);                          \
    async_copy16(Bb, &Bs[buf][0][ldB]);                                     \
    async_copy16(Bb + ((size_t)1 << 20), &Bs[buf][1][ldB]);                 \
  }

  STAGE(0, 0);
  __syncthreads();  // buffer 0 ready

  for (int t = 0; t < 128; ++t) {
    const int cur = t & 1;
    if (t < 127) STAGE(cur ^ 1, t + 1);  // prefetch next phase

    bf16x8 af[4];
#pragma unroll
    for (int i = 0; i < 4; ++i) af[i] = *(const bf16x8*)&As[cur][offA[i]];

#pragma unroll
    for (int j = 0; j < 2; ++j) {
      const bf16x8 b0 = *(const bf16x8*)&Bs[cur][0][offB[j]];
#pragma unroll
      for (int i = 0; i < 4; ++i)
        acc0[i][j] = __builtin_amdgcn_mfma_f32_16x16x32_bf16(
            af[i], b0, acc0[i][j], 0, 0, 0);
      const bf16x8 b1 = *(const bf16x8*)&Bs[cur][1][offB[j]];
#pragma unroll
      for (int i = 0; i < 4; ++i)
        acc1[i][j] = __builtin_amdgcn_mfma_f32_16x16x32_bf16(
            af[i], b1, acc1[i][j], 0, 0, 0);
    }

    if ((t & 15) == 15) {  // expert-pair epilogue (uniform branch)
      const int pair = t >> 4;
#pragma unroll
      for (int j = 0; j < 2; ++j) {
        const float bv0 = biasS[(2 * pair) * 64 + wn + j * 16 + lm];
        const float bv1 = biasS[(2 * pair + 1) * 64 + wn + j * 16 + lm];
#pragma unroll
        for (int i = 0; i < 4; ++i)
#pragma unroll
          for (int u = 0; u < 4; ++u) {
            sum[i][j][u] += fmaxf(acc0[i][j][u] + bv0, 0.f) +
                            fmaxf(acc1[i][j][u] + bv1, 0.f);
            acc0[i][j][u] = 0.f;
            acc1[i][j][u] = 0.f;
          }
      }
    }

    __syncthreads();  // drains prefetch (overlapped); guards buf reuse
  }
#undef STAGE

  // write: C/D layout col=lane&15, row=(lane>>4)*4+reg  [verified m89/m91]
  const int rbase = q * 4;
#pragma unroll
  for (int i = 0; i < 4; ++i)
#pragma unroll
    for (int j = 0; j < 2; ++j)
#pragma unroll
      for (int u = 0; u < 4; ++u)
        out[(size_t)(m0 + wm + i * 16 + rbase + u) * H_DIM + h0 + wn + j * 16 + lm] =
            sum[i][j][u];
}

// ---------------------------------------------------------------------------
// Fallback (only if workspace too small): naive but correct fp32.
// ---------------------------------------------------------------------------
__global__ __launch_bounds__(256) void naive_kernel(
    const float* __restrict__ x, const float* __restrict__ c,
    const float* __restrict__ W, const float* __restrict__ bias,
    float* __restrict__ out) {
  const int idx = blockIdx.x * 256 + threadIdx.x;
  const int b = idx >> 11;
  const int h = idx & (H_DIM - 1);
  const float* xr = x + (size_t)b * D_DIM;
  float s = 0.f;
  for (int e = 0; e < E_DIM; ++e) {
    const float* wr = W + ((size_t)e * H_DIM + h) * D_DIM;
    const float* cr = c + (size_t)e * D_DIM;
    float acc = bias[e * H_DIM + h];
    for (int d = 0; d < D_DIM; ++d) acc += (xr[d] - cr[d]) * wr[d];
    s += fmaxf(acc, 0.f);
  }
  out[idx] = s;
}

extern "C" void kernel_launch(void* const* d_in, const int* in_sizes, int n_in,
                              void* d_out, int out_size, void* d_ws, size_t ws_size,
                              hipStream_t stream) {
  const float* x = (const float*)d_in[0];     // [4096, 512]
  const float* c = (const float*)d_in[1];     // [16, 512]
  const float* W = (const float*)d_in[2];     // [16, 2048, 512]
  const float* b = (const float*)d_in[3];     // [16, 2048]
  float* out = (float*)d_out;                 // [4096, 2048]

  const size_t sz_wb = (size_t)E_DIM * H_DIM * D_DIM * 2;  // 32 MB
  const size_t sz_xb = (size_t)B_DIM * D_DIM * 2;          // 4 MB
  const size_t sz_b2 = (size_t)E_DIM * H_DIM * 4;          // 128 KB
  const size_t need = sz_wb + sz_xb + sz_b2;

  if (ws_size >= need) {
    __hip_bfloat16* Wb = (__hip_bfloat16*)((char*)d_ws);
    __hip_bfloat16* Xb = (__hip_bfloat16*)((char*)d_ws + sz_wb);
    float* bias2 = (float*)((char*)d_ws + sz_wb + sz_xb);
    prep<<<9216, 256, 0, stream>>>(W, c, b, x, Wb, bias2, Xb);
    moe_gemm<<<1024, 256, 0, stream>>>(Xb, Wb, bias2, out);
  } else {
    naive_kernel<<<(B_DIM * H_DIM) / 256, 256, 0, stream>>>(x, c, W, b, out);
  }
}